// Round 22
// baseline (98.791 us; speedup 1.0000x reference)
//
#include <hip/hip_runtime.h>

// VectorQuantizerEMA: ze (32,64,2048) f32, codebook (1024,64) f32
#define B_   32
#define D_   64
#define TP_  2048
#define K_   1024
#define N_   (B_ * TP_)          // 65536 rows
#define BETA_ 0.25f

// ws layout (float units):
//   [0,1024)        : nc2[k] (np pairwise-8)
//   [1024]/[1025]   : loss accum / ambiguous count
//   [1026]          : fix-blocks-done counter (unsigned)
//   [1088,2112)     : histogram
//   [2112,18496)    : ambiguous list
//   [18496,84032)   : pre-swizzled bf16 split-table image (16 tiles x 16KB)
#define WS_SC2   0
#define WS_LOSS  1024
#define WS_CNT   1025
#define WS_DONE  1026
#define WS_HIST  1088
#define WS_LIST  2112
#define WS_TBL   18496
#define CAP_     16384

// 3-term split dot: err ~7e-5; ref grid rounding ~1.7e-5 -> need >1.8e-4;
// 4e-4 = 2.2x headroom (R8-R20 verified). ~200 flagged rows.
#define MARGIN_  4e-4f

typedef __attribute__((ext_vector_type(8))) short short8v;   // 8 bf16
typedef __attribute__((ext_vector_type(4))) float float4v;   // C/D frag
#define AS1 __attribute__((address_space(1)))
#define AS3 __attribute__((address_space(3)))

static __device__ __forceinline__ unsigned bf16h(float f) {
    unsigned u = __float_as_uint(f);
    return (u + 0x7FFFu + ((u >> 16) & 1u)) >> 16;   // RNE to bf16
}

// ---------------- init: table chunks (blocks 0-31) + sc2/zero (32-35) --------
__global__ __attribute__((amdgpu_flat_work_group_size(256, 256)))
void vq_init(const float* __restrict__ cb, float* __restrict__ ws) {
    const int tid = threadIdx.x;
    if (blockIdx.x < 32) {
        const int gid = blockIdx.x * 256 + tid;    // [0, 8192)
        const int k = gid >> 3, i = gid & 7;       // code, 8-dim chunk
        const float4* c4 = reinterpret_cast<const float4*>(cb + (size_t)k * D_);
        unsigned short* tile = reinterpret_cast<unsigned short*>(ws + WS_TBL)
                             + (size_t)(k >> 6) * 8192;
        const int rr = k & 63;
        float4 a = c4[2 * i], b = c4[2 * i + 1];
        float v[8] = {a.x, a.y, a.z, a.w, b.x, b.y, b.z, b.w};
        short8v hi, lo;
#pragma unroll
        for (int j = 0; j < 8; ++j) {
            unsigned hu = bf16h(v[j]);
            float hf = __uint_as_float(hu << 16);
            hi[j] = (short)hu;
            lo[j] = (short)bf16h(v[j] - hf);
        }
        const int off = rr * 64 + ((8 * i) ^ ((rr & 7) << 3));
        *reinterpret_cast<short8v*>(&tile[off])        = hi;
        *reinterpret_cast<short8v*>(&tile[4096 + off]) = lo;
    } else {
        const int k = (blockIdx.x - 32) * 256 + tid;   // [0, 1024)
        const float* c = cb + (size_t)k * D_;
        // np pairwise-8, sequential i-order (bit-exact np.sum(c*c, axis=1))
        float r[8];
#pragma unroll
        for (int j = 0; j < 8; ++j) r[j] = c[j] * c[j];
#pragma unroll
        for (int i = 1; i < 8; ++i)
#pragma unroll
            for (int j = 0; j < 8; ++j) { float v = c[8 * i + j]; r[j] += v * v; }
        ws[WS_SC2 + k] = ((r[0] + r[1]) + (r[2] + r[3])) + ((r[4] + r[5]) + (r[6] + r[7]));
        reinterpret_cast<unsigned*>(ws + WS_HIST)[k] = 0u;
        if (k == 0) {
            ws[WS_LOSS] = 0.f;
            reinterpret_cast<unsigned*>(ws)[WS_CNT]  = 0u;
            reinterpret_cast<unsigned*>(ws)[WS_DONE] = 0u;
        }
    }
}

// ---------------- main: K-split barrier-free MFMA argmin + fused phase2 ------
// Exact R20 kernel (verified best: 64.5us, bench 87.6). R21's unroll/reorder
// bundle regressed (I-cache pressure signature) and was reverted.
__global__ __attribute__((amdgpu_flat_work_group_size(256, 256),
                          amdgpu_waves_per_eu(4, 4)))
void vq_main(const float* __restrict__ ze,
             const float* __restrict__ cb,
             float* __restrict__ out,
             float* __restrict__ ws) {
    __shared__ unsigned short lds[4][2][2048] __attribute__((aligned(16)));  // [wave][parity]
    __shared__ float sc2_l[K_];
    __shared__ float mbest[64], mbest2[64];
    __shared__ int   midx[64];
    __shared__ int   bidx_sh[64];
    __shared__ float nx2_sh[64];
    const int tid  = threadIdx.x;
    const int lane = tid & 63;
    const int w    = tid >> 6;         // 0..3
    const int half = w >> 1;           // code half: [half*512, +512)
    const int kg   = lane >> 4;        // k-group 0..3
    const int rc   = lane & 15;        // A-row / B-col selector
    const int n0w  = blockIdx.x * 64 + (w & 1) * 32;   // wave's first row

    // ---- A fragments, 2 rowsets: x[row = rs*16+rc][k=s*32+kg*8+e] ----
    short8v ah[2][2], al[2][2];
    float xs2[2] = {0.f, 0.f};
#pragma unroll
    for (int rs = 0; rs < 2; ++rs) {
        const int nA = n0w + rs * 16 + rc;
        const int bA = nA >> 11, tA = nA & (TP_ - 1);
        const float* zeA = ze + (size_t)bA * (D_ * TP_) + tA;
#pragma unroll
        for (int s = 0; s < 2; ++s) {
#pragma unroll
            for (int e = 0; e < 8; ++e) {
                float xv = zeA[(size_t)(s * 32 + kg * 8 + e) * TP_];
                unsigned hu = bf16h(xv);
                float hf = __uint_as_float(hu << 16);
                ah[rs][s][e] = (short)hu;
                al[rs][s][e] = (short)bf16h(xv - hf);
                xs2[rs] = fmaf(xv, xv, xs2[rs]);
            }
        }
    }
    // nx2[row]: sum xs2 across the 4 kg lanes (lane = kg*16+rc)
#pragma unroll
    for (int rs = 0; rs < 2; ++rs) {
        float v = xs2[rs];
        v += __shfl_xor(v, 16, 64);
        v += __shfl_xor(v, 32, 64);
        xs2[rs] = v;
    }
    if (half == 0 && kg == 0) {
        nx2_sh[(w & 1) * 32 + rc]      = xs2[0];
        nx2_sh[(w & 1) * 32 + 16 + rc] = xs2[1];
    }
    {
        const float* g = ws + WS_SC2 + w * 256 + lane * 4;
        __builtin_amdgcn_global_load_lds((const AS1 unsigned int*)g,
                                         (AS3 unsigned int*)&sc2_l[w * 256], 16, 0, 0);
    }
    const unsigned short* img = reinterpret_cast<const unsigned short*>(ws + WS_TBL);

    float best[2][4], best2[2][4];
    int   bidx[2][4];
#pragma unroll
    for (int rs = 0; rs < 2; ++rs)
#pragma unroll
        for (int r = 0; r < 4; ++r) {
            best[rs][r] = 3.4e38f; best2[rs][r] = 3.4e38f; bidx[rs][r] = 0;
        }

    // stage 16-code tile t of this wave's half: 4KB = 4 x global_load_lds
#define STAGE(t) do {                                                             \
        const int _g0 = half * 512 + (t) * 16;                                    \
        const unsigned short* _src = img + (size_t)(_g0 >> 6) * 8192              \
                                         + (size_t)(_g0 & 63) * 64;               \
        unsigned short* _d = lds[w][(t) & 1];                                     \
        _Pragma("unroll")                                                         \
        for (int _c = 0; _c < 2; ++_c) {                                          \
            __builtin_amdgcn_global_load_lds(                                     \
                (const AS1 unsigned int*)(_src + _c * 512 + lane * 8),            \
                (AS3 unsigned int*)(_d + _c * 512), 16, 0, 0);                    \
            __builtin_amdgcn_global_load_lds(                                     \
                (const AS1 unsigned int*)(_src + 4096 + _c * 512 + lane * 8),     \
                (AS3 unsigned int*)(_d + 1024 + _c * 512), 16, 0, 0);             \
        }                                                                         \
    } while (0)

    // tile t: 4 ds_read_b128, lgkm WAR drain, re-stage t+2, 12 MFMA, argmin
#define TILE(t) do {                                                              \
        const unsigned short* _b = lds[w][(t) & 1];                               \
        const int cx0 = (kg * 8) ^ ((rc & 7) << 3);                               \
        const int cx1 = (32 + kg * 8) ^ ((rc & 7) << 3);                          \
        short8v bh0 = *reinterpret_cast<const short8v*>(_b + rc * 64 + cx0);      \
        short8v bh1 = *reinterpret_cast<const short8v*>(_b + rc * 64 + cx1);      \
        short8v bl0 = *reinterpret_cast<const short8v*>(_b + 1024 + rc * 64 + cx0); \
        short8v bl1 = *reinterpret_cast<const short8v*>(_b + 1024 + rc * 64 + cx1); \
        asm volatile("s_waitcnt lgkmcnt(0)" ::: "memory");  /* WAR before re-stage */ \
        if ((t) < 30) STAGE((t) + 2);                                             \
        const int code = half * 512 + (t) * 16 + rc;                              \
        const float s2 = sc2_l[code];                                             \
        _Pragma("unroll")                                                         \
        for (int rs = 0; rs < 2; ++rs) {                                          \
            float4v aH = {0.f, 0.f, 0.f, 0.f};                                    \
            float4v aL = {0.f, 0.f, 0.f, 0.f};                                    \
            aH = __builtin_amdgcn_mfma_f32_16x16x32_bf16(ah[rs][0], bh0, aH, 0, 0, 0); \
            aL = __builtin_amdgcn_mfma_f32_16x16x32_bf16(al[rs][0], bh0, aL, 0, 0, 0); \
            aH = __builtin_amdgcn_mfma_f32_16x16x32_bf16(ah[rs][1], bh1, aH, 0, 0, 0); \
            aL = __builtin_amdgcn_mfma_f32_16x16x32_bf16(al[rs][1], bh1, aL, 0, 0, 0); \
            aH = __builtin_amdgcn_mfma_f32_16x16x32_bf16(ah[rs][0], bl0, aH, 0, 0, 0); \
            aH = __builtin_amdgcn_mfma_f32_16x16x32_bf16(ah[rs][1], bl1, aH, 0, 0, 0); \
            _Pragma("unroll")                                                     \
            for (int r = 0; r < 4; ++r) {                                         \
                float v = fmaf(-2.f, aH[r] + aL[r], s2);                          \
                if (v < best[rs][r]) { best2[rs][r] = best[rs][r];                \
                    best[rs][r] = v; bidx[rs][r] = code; }                        \
                else if (v < best2[rs][r]) best2[rs][r] = v;                      \
            }                                                                     \
        }                                                                         \
    } while (0)

    __syncthreads();                  // drain A-loads + sc2 stage; publish sc2_l/nx2
    STAGE(0); STAGE(1);               // 8 outstanding
    for (int t = 0; t < 31; ++t) {
        asm volatile("s_waitcnt vmcnt(4)" ::: "memory");  // tile t retired
        TILE(t);
    }
    asm volatile("s_waitcnt vmcnt(0)" ::: "memory");
    TILE(31);
#undef STAGE
#undef TILE

    // reduce (best,best2,idx) across the 16 cols (low 4 lane bits)
#pragma unroll
    for (int rs = 0; rs < 2; ++rs)
#pragma unroll
    for (int r = 0; r < 4; ++r) {
        unsigned fu = __float_as_uint(best[rs][r]);
        fu = (fu & 0x80000000u) ? ~fu : (fu | 0x80000000u);
        unsigned long long pk = ((unsigned long long)fu << 32) | (unsigned)bidx[rs][r];
        float bf = best[rs][r], b2 = best2[rs][r];
#pragma unroll
        for (int m = 1; m <= 8; m <<= 1) {
            unsigned long long po = __shfl_xor(pk, m, 64);
            float bo  = __shfl_xor(bf, m, 64);
            float b2o = __shfl_xor(b2, m, 64);
            b2 = fminf(fminf(b2, b2o), fmaxf(bf, bo));
            bf = fminf(bf, bo);
            if (po < pk) pk = po;
        }
        best[rs][r] = bf; best2[rs][r] = b2; bidx[rs][r] = (int)(pk & 0x3FFull);
    }

    // half-1 posts per-row results; half-0 merges (lower codes win ties)
    if (half == 1 && rc == 0) {
#pragma unroll
        for (int rs = 0; rs < 2; ++rs)
#pragma unroll
        for (int r = 0; r < 4; ++r) {
            const int rowb = (w & 1) * 32 + rs * 16 + kg * 4 + r;
            mbest[rowb]  = best[rs][r];
            mbest2[rowb] = best2[rs][r];
            midx[rowb]   = bidx[rs][r];
        }
    }
    __syncthreads();

    if (half == 0 && rc == 0) {
        unsigned* gh = reinterpret_cast<unsigned*>(ws + WS_HIST);
#pragma unroll
        for (int rs = 0; rs < 2; ++rs)
#pragma unroll
        for (int r = 0; r < 4; ++r) {
            const int rowb = (w & 1) * 32 + rs * 16 + kg * 4 + r;
            const int n    = blockIdx.x * 64 + rowb;
            float bA = best[rs][r],  b2A = best2[rs][r];
            float bB = mbest[rowb],  b2B = mbest2[rowb];
            int   iM = (bB < bA) ? midx[rowb] : bidx[rs][r];
            float bM  = fminf(bA, bB);
            float b2M = fminf(fminf(b2A, b2B), fmaxf(bA, bB));
            out[(size_t)N_ * D_ + n] = (float)iM;      // token id (pre-fix)
            atomicAdd(&gh[iM], 1u);
            if (b2M - bM < MARGIN_) {
                unsigned slot = atomicAdd(reinterpret_cast<unsigned*>(ws) + WS_CNT, 1u);
                if (slot < CAP_)
                    reinterpret_cast<unsigned*>(ws + WS_LIST)[slot] =
                        ((unsigned)n << 10) | (unsigned)iM;
            }
            bidx_sh[rowb] = iM;
            mbest[rowb]   = bM;        // chosen distance (discriminant) for loss
        }
    }
    __syncthreads();

    // ---- phase2 (fused): zq gather-write; loss = nx2 + best (no ze re-read) --
    const int row   = tid & 63;
    const int chunk = tid >> 6;                    // dims [chunk*16, +16)
    const int n2 = blockIdx.x * 64 + row;
    const int b2i = n2 >> 11, t2 = n2 & (TP_ - 1);
    const int k2 = bidx_sh[row];
    float* outr = out + (size_t)b2i * (D_ * TP_) + t2;
    const float4* cr4 = reinterpret_cast<const float4*>(cb + (size_t)k2 * D_ + chunk * 16);
#pragma unroll
    for (int q4 = 0; q4 < 4; ++q4) {
        float4 q = cr4[q4];
        float qv[4] = {q.x, q.y, q.z, q.w};
#pragma unroll
        for (int c = 0; c < 4; ++c) {
            const int d = chunk * 16 + q4 * 4 + c;
            outr[(size_t)d * TP_] = qv[c];         // ze + (zq - ze) == zq
        }
    }
    if (w == 0) {                                  // one wave: per-row loss
        float lsum = nx2_sh[lane] + mbest[lane];   // ||x||^2 + (||c||^2 - 2x.c)
#pragma unroll
        for (int m = 32; m >= 1; m >>= 1) lsum += __shfl_xor(lsum, m, 64);
        if (lane == 0) atomicAdd(ws + WS_LOSS, lsum);
    }
}

// ---------------- fixup + fused finalize (last block done) -------------------
// R22: vq_fin folded in. All 256 blocks bump a done-counter; the last one
// computes perplexity/loss scalars. Hist/loss were only ever written by
// device-scope atomics; re-read via atomicAdd(ptr,0) for cross-XCD coherence.
__global__ __attribute__((amdgpu_flat_work_group_size(256, 256)))
void vq_fix(const float* __restrict__ ze,
            const float* __restrict__ cb,
            float* __restrict__ out,
            float* __restrict__ ws) {
    __shared__ float xls[64] __attribute__((aligned(16)));
    __shared__ unsigned long long wmin[4];
    __shared__ float gdist;
    __shared__ int gks;
    __shared__ int lastdone;
    __shared__ double red[256];
    const int tid  = threadIdx.x;
    const int lane = tid & 63;
    const int wl   = tid >> 6;
    unsigned cnt = reinterpret_cast<const unsigned*>(ws)[WS_CNT];
    if (cnt > CAP_) cnt = CAP_;
    const unsigned* list = reinterpret_cast<const unsigned*>(ws + WS_LIST);
    const float* sc2 = ws + WS_SC2;
    unsigned* gh = reinterpret_cast<unsigned*>(ws + WS_HIST);

    for (unsigned i = blockIdx.x; i < cnt; i += 256) {
        unsigned e = list[i];
        const int n     = (int)(e >> 10);
        const int guess = (int)(e & 1023u);
        const int b  = n >> 11;
        const int tp = n & (TP_ - 1);
        const float* zp = ze + (size_t)b * D_ * TP_ + tp;

        if (tid < 64) xls[tid] = zp[(size_t)tid * TP_];
        __syncthreads();

        // np pairwise-8 ||x||^2 (bit-exact np.sum(x*x, axis=1))
        float r[8];
#pragma unroll
        for (int j = 0; j < 8; ++j) { float v = xls[j]; r[j] = v * v; }
#pragma unroll
        for (int ii = 1; ii < 8; ++ii)
#pragma unroll
            for (int j = 0; j < 8; ++j) { float v = xls[8 * ii + j]; r[j] += v * v; }
        float nx2 = ((r[0] + r[1]) + (r[2] + r[3])) + ((r[4] + r[5]) + (r[6] + r[7]));

        const float4* x4 = reinterpret_cast<const float4*>(xls);
        unsigned long long m = ~0ull;
#pragma unroll
        for (int kk = 0; kk < 4; ++kk) {
            const int k = tid * 4 + kk;
            const float4* cp4 = reinterpret_cast<const float4*>(cb + (size_t)k * D_);
            double a0 = 0.0, a1 = 0.0, a2 = 0.0, a3 = 0.0;
#pragma unroll 4
            for (int j4 = 0; j4 < 16; ++j4) {      // capped unroll: VGPR sane
                float4 xv = x4[j4];
                float4 cv = cp4[j4];
                a0 = fma((double)xv.x, (double)cv.x, a0);
                a1 = fma((double)xv.y, (double)cv.y, a1);
                a2 = fma((double)xv.z, (double)cv.z, a2);
                a3 = fma((double)xv.w, (double)cv.w, a3);
            }
            float dotf = (float)((a0 + a1) + (a2 + a3));
            float A    = nx2 + sc2[k];
            float dist = A - 2.0f * dotf;          // ref grid arithmetic
            if (k == guess) gdist = dist;
            unsigned long long pk =
                ((unsigned long long)__float_as_uint(dist) << 32) | (unsigned)k;
            if (pk < m) m = pk;
        }
#pragma unroll
        for (int s = 32; s >= 1; s >>= 1) {
            unsigned long long o = __shfl_xor(m, s, 64);
            if (o < m) m = o;
        }
        if (lane == 0) wmin[wl] = m;
        __syncthreads();
        if (tid == 0) {
            unsigned long long mm = wmin[0];
            if (wmin[1] < mm) mm = wmin[1];
            if (wmin[2] < mm) mm = wmin[2];
            if (wmin[3] < mm) mm = wmin[3];
            gks = (int)(mm & 1023ull);
            const int gk = gks;
            if (gk != guess) {
                float dgk = __uint_as_float((unsigned)(mm >> 32));
                atomicAdd(ws + WS_LOSS, dgk - gdist);   // grid-dist loss delta
                out[(size_t)N_ * D_ + n] = (float)gk;
                atomicSub(&gh[guess], 1u);
                atomicAdd(&gh[gk], 1u);
            }
        }
        __syncthreads();
        const int gk = gks;
        if (gk != guess && tid < 64) {
            out[(size_t)b * D_ * TP_ + (size_t)tid * TP_ + tp] = cb[(size_t)gk * D_ + tid];
        }
        __syncthreads();               // xls reuse guard
    }

    // ---- last-block-done finalize ----
    __threadfence();
    if (tid == 0) {
        unsigned done = atomicAdd(reinterpret_cast<unsigned*>(ws) + WS_DONE, 1u);
        lastdone = (done == gridDim.x - 1);
    }
    __syncthreads();
    if (!lastdone) return;

    double s = 0.0;
#pragma unroll
    for (int kk = 0; kk < 4; ++kk) {
        const int k = tid * 4 + kk;
        unsigned c = atomicAdd(&gh[k], 0u);       // coherent cross-XCD read
        double p = (double)c * (1.0 / (double)N_);
        s += -p * log(p + 1e-10);
    }
    red[tid] = s;
    __syncthreads();
    for (int st = 128; st > 0; st >>= 1) {
        if (tid < st) red[tid] += red[tid + st];
        __syncthreads();
    }
    if (tid == 0) {
        float loss = atomicAdd(ws + WS_LOSS, 0.f);   // coherent read
        out[(size_t)N_ * D_ + N_]     = BETA_ * loss * (1.0f / (float)(N_ * D_));
        out[(size_t)N_ * D_ + N_ + 1] = (float)exp(red[0]);
    }
}

extern "C" void kernel_launch(void* const* d_in, const int* in_sizes, int n_in,
                              void* d_out, int out_size, void* d_ws, size_t ws_size,
                              hipStream_t stream) {
    const float* ze = (const float*)d_in[0];
    const float* cb = (const float*)d_in[1];
    float* out = (float*)d_out;
    float* ws  = (float*)d_ws;

    vq_init<<<dim3(36), dim3(256), 0, stream>>>(cb, ws);
    vq_main<<<dim3(N_ / 64), dim3(256), 0, stream>>>(ze, cb, out, ws);
    vq_fix<<<dim3(256), dim3(256), 0, stream>>>(ze, cb, out, ws);
}

// Round 23
// 87.425 us; speedup vs baseline: 1.1300x; 1.1300x over previous
//
#include <hip/hip_runtime.h>

// VectorQuantizerEMA: ze (32,64,2048) f32, codebook (1024,64) f32
#define B_   32
#define D_   64
#define TP_  2048
#define K_   1024
#define N_   (B_ * TP_)          // 65536 rows
#define BETA_ 0.25f

// ws layout (float units):
//   [0,1024)        : nc2[k] (np pairwise-8)
//   [1024]/[1025]   : loss accum / ambiguous count
//   [1088,2112)     : histogram
//   [2112,18496)    : ambiguous list
//   [18496,84032)   : pre-swizzled bf16 split-table image (16 tiles x 16KB)
#define WS_SC2   0
#define WS_LOSS  1024
#define WS_CNT   1025
#define WS_HIST  1088
#define WS_LIST  2112
#define WS_TBL   18496
#define CAP_     16384

// 3-term split dot: err ~7e-5; ref grid rounding ~1.7e-5 -> need >1.8e-4;
// 4e-4 = 2.2x headroom (R8-R20 verified). ~200 flagged rows.
#define MARGIN_  4e-4f

typedef __attribute__((ext_vector_type(8))) short short8v;   // 8 bf16
typedef __attribute__((ext_vector_type(4))) float float4v;   // C/D frag
#define AS1 __attribute__((address_space(1)))
#define AS3 __attribute__((address_space(3)))

static __device__ __forceinline__ unsigned bf16h(float f) {
    unsigned u = __float_as_uint(f);
    return (u + 0x7FFFu + ((u >> 16) & 1u)) >> 16;   // RNE to bf16
}

// ---------------- init: table chunks (blocks 0-31) + sc2/zero (32-35) --------
__global__ __attribute__((amdgpu_flat_work_group_size(256, 256)))
void vq_init(const float* __restrict__ cb, float* __restrict__ ws) {
    const int tid = threadIdx.x;
    if (blockIdx.x < 32) {
        const int gid = blockIdx.x * 256 + tid;    // [0, 8192)
        const int k = gid >> 3, i = gid & 7;       // code, 8-dim chunk
        const float4* c4 = reinterpret_cast<const float4*>(cb + (size_t)k * D_);
        unsigned short* tile = reinterpret_cast<unsigned short*>(ws + WS_TBL)
                             + (size_t)(k >> 6) * 8192;
        const int rr = k & 63;
        float4 a = c4[2 * i], b = c4[2 * i + 1];
        float v[8] = {a.x, a.y, a.z, a.w, b.x, b.y, b.z, b.w};
        short8v hi, lo;
#pragma unroll
        for (int j = 0; j < 8; ++j) {
            unsigned hu = bf16h(v[j]);
            float hf = __uint_as_float(hu << 16);
            hi[j] = (short)hu;
            lo[j] = (short)bf16h(v[j] - hf);
        }
        const int off = rr * 64 + ((8 * i) ^ ((rr & 7) << 3));
        *reinterpret_cast<short8v*>(&tile[off])        = hi;
        *reinterpret_cast<short8v*>(&tile[4096 + off]) = lo;
    } else {
        const int k = (blockIdx.x - 32) * 256 + tid;   // [0, 1024)
        const float* c = cb + (size_t)k * D_;
        // np pairwise-8, sequential i-order (bit-exact np.sum(c*c, axis=1))
        float r[8];
#pragma unroll
        for (int j = 0; j < 8; ++j) r[j] = c[j] * c[j];
#pragma unroll
        for (int i = 1; i < 8; ++i)
#pragma unroll
            for (int j = 0; j < 8; ++j) { float v = c[8 * i + j]; r[j] += v * v; }
        ws[WS_SC2 + k] = ((r[0] + r[1]) + (r[2] + r[3])) + ((r[4] + r[5]) + (r[6] + r[7]));
        reinterpret_cast<unsigned*>(ws + WS_HIST)[k] = 0u;
        if (k == 0) {
            ws[WS_LOSS] = 0.f;
            reinterpret_cast<unsigned*>(ws)[WS_CNT] = 0u;
        }
    }
}

// ---------------- main: K-split barrier-free MFMA argmin + fused phase2 ------
// Exact R20 kernel (verified best: main 64.5us, bench 87.6). R21 (unroll/
// setprio/reorder) and R22 (fin fusion w/ threadfence) both regressed in A/B
// and are reverted.
__global__ __attribute__((amdgpu_flat_work_group_size(256, 256),
                          amdgpu_waves_per_eu(4, 4)))
void vq_main(const float* __restrict__ ze,
             const float* __restrict__ cb,
             float* __restrict__ out,
             float* __restrict__ ws) {
    __shared__ unsigned short lds[4][2][2048] __attribute__((aligned(16)));  // [wave][parity]
    __shared__ float sc2_l[K_];
    __shared__ float mbest[64], mbest2[64];
    __shared__ int   midx[64];
    __shared__ int   bidx_sh[64];
    __shared__ float nx2_sh[64];
    const int tid  = threadIdx.x;
    const int lane = tid & 63;
    const int w    = tid >> 6;         // 0..3
    const int half = w >> 1;           // code half: [half*512, +512)
    const int kg   = lane >> 4;        // k-group 0..3
    const int rc   = lane & 15;        // A-row / B-col selector
    const int n0w  = blockIdx.x * 64 + (w & 1) * 32;   // wave's first row

    // ---- A fragments, 2 rowsets: x[row = rs*16+rc][k=s*32+kg*8+e] ----
    short8v ah[2][2], al[2][2];
    float xs2[2] = {0.f, 0.f};
#pragma unroll
    for (int rs = 0; rs < 2; ++rs) {
        const int nA = n0w + rs * 16 + rc;
        const int bA = nA >> 11, tA = nA & (TP_ - 1);
        const float* zeA = ze + (size_t)bA * (D_ * TP_) + tA;
#pragma unroll
        for (int s = 0; s < 2; ++s) {
#pragma unroll
            for (int e = 0; e < 8; ++e) {
                float xv = zeA[(size_t)(s * 32 + kg * 8 + e) * TP_];
                unsigned hu = bf16h(xv);
                float hf = __uint_as_float(hu << 16);
                ah[rs][s][e] = (short)hu;
                al[rs][s][e] = (short)bf16h(xv - hf);
                xs2[rs] = fmaf(xv, xv, xs2[rs]);
            }
        }
    }
    // nx2[row]: sum xs2 across the 4 kg lanes (lane = kg*16+rc)
#pragma unroll
    for (int rs = 0; rs < 2; ++rs) {
        float v = xs2[rs];
        v += __shfl_xor(v, 16, 64);
        v += __shfl_xor(v, 32, 64);
        xs2[rs] = v;
    }
    if (half == 0 && kg == 0) {
        nx2_sh[(w & 1) * 32 + rc]      = xs2[0];
        nx2_sh[(w & 1) * 32 + 16 + rc] = xs2[1];
    }
    {
        const float* g = ws + WS_SC2 + w * 256 + lane * 4;
        __builtin_amdgcn_global_load_lds((const AS1 unsigned int*)g,
                                         (AS3 unsigned int*)&sc2_l[w * 256], 16, 0, 0);
    }
    const unsigned short* img = reinterpret_cast<const unsigned short*>(ws + WS_TBL);

    float best[2][4], best2[2][4];
    int   bidx[2][4];
#pragma unroll
    for (int rs = 0; rs < 2; ++rs)
#pragma unroll
        for (int r = 0; r < 4; ++r) {
            best[rs][r] = 3.4e38f; best2[rs][r] = 3.4e38f; bidx[rs][r] = 0;
        }

    // stage 16-code tile t of this wave's half: 4KB = 4 x global_load_lds
#define STAGE(t) do {                                                             \
        const int _g0 = half * 512 + (t) * 16;                                    \
        const unsigned short* _src = img + (size_t)(_g0 >> 6) * 8192              \
                                         + (size_t)(_g0 & 63) * 64;               \
        unsigned short* _d = lds[w][(t) & 1];                                     \
        _Pragma("unroll")                                                         \
        for (int _c = 0; _c < 2; ++_c) {                                          \
            __builtin_amdgcn_global_load_lds(                                     \
                (const AS1 unsigned int*)(_src + _c * 512 + lane * 8),            \
                (AS3 unsigned int*)(_d + _c * 512), 16, 0, 0);                    \
            __builtin_amdgcn_global_load_lds(                                     \
                (const AS1 unsigned int*)(_src + 4096 + _c * 512 + lane * 8),     \
                (AS3 unsigned int*)(_d + 1024 + _c * 512), 16, 0, 0);             \
        }                                                                         \
    } while (0)

    // tile t: 4 ds_read_b128, lgkm WAR drain, re-stage t+2, 12 MFMA, argmin
#define TILE(t) do {                                                              \
        const unsigned short* _b = lds[w][(t) & 1];                               \
        const int cx0 = (kg * 8) ^ ((rc & 7) << 3);                               \
        const int cx1 = (32 + kg * 8) ^ ((rc & 7) << 3);                          \
        short8v bh0 = *reinterpret_cast<const short8v*>(_b + rc * 64 + cx0);      \
        short8v bh1 = *reinterpret_cast<const short8v*>(_b + rc * 64 + cx1);      \
        short8v bl0 = *reinterpret_cast<const short8v*>(_b + 1024 + rc * 64 + cx0); \
        short8v bl1 = *reinterpret_cast<const short8v*>(_b + 1024 + rc * 64 + cx1); \
        asm volatile("s_waitcnt lgkmcnt(0)" ::: "memory");  /* WAR before re-stage */ \
        if ((t) < 30) STAGE((t) + 2);                                             \
        const int code = half * 512 + (t) * 16 + rc;                              \
        const float s2 = sc2_l[code];                                             \
        _Pragma("unroll")                                                         \
        for (int rs = 0; rs < 2; ++rs) {                                          \
            float4v aH = {0.f, 0.f, 0.f, 0.f};                                    \
            float4v aL = {0.f, 0.f, 0.f, 0.f};                                    \
            aH = __builtin_amdgcn_mfma_f32_16x16x32_bf16(ah[rs][0], bh0, aH, 0, 0, 0); \
            aL = __builtin_amdgcn_mfma_f32_16x16x32_bf16(al[rs][0], bh0, aL, 0, 0, 0); \
            aH = __builtin_amdgcn_mfma_f32_16x16x32_bf16(ah[rs][1], bh1, aH, 0, 0, 0); \
            aL = __builtin_amdgcn_mfma_f32_16x16x32_bf16(al[rs][1], bh1, aL, 0, 0, 0); \
            aH = __builtin_amdgcn_mfma_f32_16x16x32_bf16(ah[rs][0], bl0, aH, 0, 0, 0); \
            aH = __builtin_amdgcn_mfma_f32_16x16x32_bf16(ah[rs][1], bl1, aH, 0, 0, 0); \
            _Pragma("unroll")                                                     \
            for (int r = 0; r < 4; ++r) {                                         \
                float v = fmaf(-2.f, aH[r] + aL[r], s2);                          \
                if (v < best[rs][r]) { best2[rs][r] = best[rs][r];                \
                    best[rs][r] = v; bidx[rs][r] = code; }                        \
                else if (v < best2[rs][r]) best2[rs][r] = v;                      \
            }                                                                     \
        }                                                                         \
    } while (0)

    __syncthreads();                  // drain A-loads + sc2 stage; publish sc2_l/nx2
    STAGE(0); STAGE(1);               // 8 outstanding
    for (int t = 0; t < 31; ++t) {
        asm volatile("s_waitcnt vmcnt(4)" ::: "memory");  // tile t retired
        TILE(t);
    }
    asm volatile("s_waitcnt vmcnt(0)" ::: "memory");
    TILE(31);
#undef STAGE
#undef TILE

    // reduce (best,best2,idx) across the 16 cols (low 4 lane bits)
#pragma unroll
    for (int rs = 0; rs < 2; ++rs)
#pragma unroll
    for (int r = 0; r < 4; ++r) {
        unsigned fu = __float_as_uint(best[rs][r]);
        fu = (fu & 0x80000000u) ? ~fu : (fu | 0x80000000u);
        unsigned long long pk = ((unsigned long long)fu << 32) | (unsigned)bidx[rs][r];
        float bf = best[rs][r], b2 = best2[rs][r];
#pragma unroll
        for (int m = 1; m <= 8; m <<= 1) {
            unsigned long long po = __shfl_xor(pk, m, 64);
            float bo  = __shfl_xor(bf, m, 64);
            float b2o = __shfl_xor(b2, m, 64);
            b2 = fminf(fminf(b2, b2o), fmaxf(bf, bo));
            bf = fminf(bf, bo);
            if (po < pk) pk = po;
        }
        best[rs][r] = bf; best2[rs][r] = b2; bidx[rs][r] = (int)(pk & 0x3FFull);
    }

    // half-1 posts per-row results; half-0 merges (lower codes win ties)
    if (half == 1 && rc == 0) {
#pragma unroll
        for (int rs = 0; rs < 2; ++rs)
#pragma unroll
        for (int r = 0; r < 4; ++r) {
            const int rowb = (w & 1) * 32 + rs * 16 + kg * 4 + r;
            mbest[rowb]  = best[rs][r];
            mbest2[rowb] = best2[rs][r];
            midx[rowb]   = bidx[rs][r];
        }
    }
    __syncthreads();

    if (half == 0 && rc == 0) {
        unsigned* gh = reinterpret_cast<unsigned*>(ws + WS_HIST);
#pragma unroll
        for (int rs = 0; rs < 2; ++rs)
#pragma unroll
        for (int r = 0; r < 4; ++r) {
            const int rowb = (w & 1) * 32 + rs * 16 + kg * 4 + r;
            const int n    = blockIdx.x * 64 + rowb;
            float bA = best[rs][r],  b2A = best2[rs][r];
            float bB = mbest[rowb],  b2B = mbest2[rowb];
            int   iM = (bB < bA) ? midx[rowb] : bidx[rs][r];
            float bM  = fminf(bA, bB);
            float b2M = fminf(fminf(b2A, b2B), fmaxf(bA, bB));
            out[(size_t)N_ * D_ + n] = (float)iM;      // token id (pre-fix)
            atomicAdd(&gh[iM], 1u);
            if (b2M - bM < MARGIN_) {
                unsigned slot = atomicAdd(reinterpret_cast<unsigned*>(ws) + WS_CNT, 1u);
                if (slot < CAP_)
                    reinterpret_cast<unsigned*>(ws + WS_LIST)[slot] =
                        ((unsigned)n << 10) | (unsigned)iM;
            }
            bidx_sh[rowb] = iM;
            mbest[rowb]   = bM;        // chosen distance (discriminant) for loss
        }
    }
    __syncthreads();

    // ---- phase2 (fused): zq gather-write; loss = nx2 + best (no ze re-read) --
    const int row   = tid & 63;
    const int chunk = tid >> 6;                    // dims [chunk*16, +16)
    const int n2 = blockIdx.x * 64 + row;
    const int b2i = n2 >> 11, t2 = n2 & (TP_ - 1);
    const int k2 = bidx_sh[row];
    float* outr = out + (size_t)b2i * (D_ * TP_) + t2;
    const float4* cr4 = reinterpret_cast<const float4*>(cb + (size_t)k2 * D_ + chunk * 16);
#pragma unroll
    for (int q4 = 0; q4 < 4; ++q4) {
        float4 q = cr4[q4];
        float qv[4] = {q.x, q.y, q.z, q.w};
#pragma unroll
        for (int c = 0; c < 4; ++c) {
            const int d = chunk * 16 + q4 * 4 + c;
            outr[(size_t)d * TP_] = qv[c];         // ze + (zq - ze) == zq
        }
    }
    if (w == 0) {                                  // one wave: per-row loss
        float lsum = nx2_sh[lane] + mbest[lane];   // ||x||^2 + (||c||^2 - 2x.c)
#pragma unroll
        for (int m = 32; m >= 1; m >>= 1) lsum += __shfl_xor(lsum, m, 64);
        if (lane == 0) atomicAdd(ws + WS_LOSS, lsum);
    }
}

// ---------------- fixup: ref-grid argmin; patches token+zq+loss+hist ---------
__global__ __attribute__((amdgpu_flat_work_group_size(256, 256)))
void vq_fix(const float* __restrict__ ze,
            const float* __restrict__ cb,
            float* __restrict__ out,
            float* __restrict__ ws) {
    __shared__ float xls[64] __attribute__((aligned(16)));
    __shared__ unsigned long long wmin[4];
    __shared__ float gdist;
    __shared__ int gks;
    const int tid  = threadIdx.x;
    const int lane = tid & 63;
    const int wl   = tid >> 6;
    unsigned cnt = reinterpret_cast<const unsigned*>(ws)[WS_CNT];
    if (cnt > CAP_) cnt = CAP_;
    const unsigned* list = reinterpret_cast<const unsigned*>(ws + WS_LIST);
    const float* sc2 = ws + WS_SC2;
    unsigned* gh = reinterpret_cast<unsigned*>(ws + WS_HIST);

    for (unsigned i = blockIdx.x; i < cnt; i += 256) {
        unsigned e = list[i];
        const int n     = (int)(e >> 10);
        const int guess = (int)(e & 1023u);
        const int b  = n >> 11;
        const int tp = n & (TP_ - 1);
        const float* zp = ze + (size_t)b * D_ * TP_ + tp;

        if (tid < 64) xls[tid] = zp[(size_t)tid * TP_];
        __syncthreads();

        // np pairwise-8 ||x||^2 (bit-exact np.sum(x*x, axis=1))
        float r[8];
#pragma unroll
        for (int j = 0; j < 8; ++j) { float v = xls[j]; r[j] = v * v; }
#pragma unroll
        for (int ii = 1; ii < 8; ++ii)
#pragma unroll
            for (int j = 0; j < 8; ++j) { float v = xls[8 * ii + j]; r[j] += v * v; }
        float nx2 = ((r[0] + r[1]) + (r[2] + r[3])) + ((r[4] + r[5]) + (r[6] + r[7]));

        const float4* x4 = reinterpret_cast<const float4*>(xls);
        unsigned long long m = ~0ull;
#pragma unroll
        for (int kk = 0; kk < 4; ++kk) {
            const int k = tid * 4 + kk;
            const float4* cp4 = reinterpret_cast<const float4*>(cb + (size_t)k * D_);
            double a0 = 0.0, a1 = 0.0, a2 = 0.0, a3 = 0.0;
#pragma unroll 4
            for (int j4 = 0; j4 < 16; ++j4) {      // capped unroll: VGPR sane
                float4 xv = x4[j4];
                float4 cv = cp4[j4];
                a0 = fma((double)xv.x, (double)cv.x, a0);
                a1 = fma((double)xv.y, (double)cv.y, a1);
                a2 = fma((double)xv.z, (double)cv.z, a2);
                a3 = fma((double)xv.w, (double)cv.w, a3);
            }
            float dotf = (float)((a0 + a1) + (a2 + a3));
            float A    = nx2 + sc2[k];
            float dist = A - 2.0f * dotf;          // ref grid arithmetic
            if (k == guess) gdist = dist;
            unsigned long long pk =
                ((unsigned long long)__float_as_uint(dist) << 32) | (unsigned)k;
            if (pk < m) m = pk;
        }
#pragma unroll
        for (int s = 32; s >= 1; s >>= 1) {
            unsigned long long o = __shfl_xor(m, s, 64);
            if (o < m) m = o;
        }
        if (lane == 0) wmin[wl] = m;
        __syncthreads();
        if (tid == 0) {
            unsigned long long mm = wmin[0];
            if (wmin[1] < mm) mm = wmin[1];
            if (wmin[2] < mm) mm = wmin[2];
            if (wmin[3] < mm) mm = wmin[3];
            gks = (int)(mm & 1023ull);
            const int gk = gks;
            if (gk != guess) {
                float dgk = __uint_as_float((unsigned)(mm >> 32));
                atomicAdd(ws + WS_LOSS, dgk - gdist);   // grid-dist loss delta
                out[(size_t)N_ * D_ + n] = (float)gk;
                atomicSub(&gh[guess], 1u);
                atomicAdd(&gh[gk], 1u);
            }
        }
        __syncthreads();
        const int gk = gks;
        if (gk != guess && tid < 64) {
            out[(size_t)b * D_ * TP_ + (size_t)tid * TP_ + tp] = cb[(size_t)gk * D_ + tid];
        }
        __syncthreads();               // xls reuse guard
    }
}

// ---------------- finalize: scalars ----------------
__global__ void vq_fin(const float* __restrict__ ws, float* __restrict__ out) {
    __shared__ double red[K_];
    const int t = threadIdx.x;
    const unsigned* gh = reinterpret_cast<const unsigned*>(ws + WS_HIST);
    double p = (double)gh[t] * (1.0 / (double)N_);
    red[t] = -p * log(p + 1e-10);
    __syncthreads();
    for (int s = 512; s > 0; s >>= 1) {
        if (t < s) red[t] += red[t + s];
        __syncthreads();
    }
    if (t == 0) {
        out[(size_t)N_ * D_ + N_]     = BETA_ * ws[WS_LOSS] * (1.0f / (float)(N_ * D_));
        out[(size_t)N_ * D_ + N_ + 1] = (float)exp(red[0]);
    }
}

extern "C" void kernel_launch(void* const* d_in, const int* in_sizes, int n_in,
                              void* d_out, int out_size, void* d_ws, size_t ws_size,
                              hipStream_t stream) {
    const float* ze = (const float*)d_in[0];
    const float* cb = (const float*)d_in[1];
    float* out = (float*)d_out;
    float* ws  = (float*)d_ws;

    vq_init<<<dim3(36), dim3(256), 0, stream>>>(cb, ws);
    vq_main<<<dim3(N_ / 64), dim3(256), 0, stream>>>(ze, cb, out, ws);
    vq_fix<<<dim3(256), dim3(256), 0, stream>>>(ze, cb, out, ws);
    vq_fin<<<dim3(1), dim3(K_), 0, stream>>>(ws, out);
}